// Round 5
// baseline (1472.994 us; speedup 1.0000x reference)
//
#include <hip/hip_runtime.h>

// ---------------------------------------------------------------------------
// Nystrom attention, fp32. b=2,h=8,n=8192,d=64, m=256 landmarks, conv33.
// Round 5: persistent pinv mega-kernel (atomic grid barrier), 2-block/CU
// flash kernels (128-row tiles, 4x8 micro).
// ---------------------------------------------------------------------------

#define N_SEQ 8192
#define NBH   16
#define MLAND 256
#define DHEAD 64

// flash kernels' shared layout (floats): Qt [64][132] | KP [64][68] | WC [64][68]
#define QT_STRIDE 132
#define KP_OFF    8448           // 64*132
#define WC_OFF    12800          // + 64*68
#define FL_SMEM   17152          // + 64*68  (68.6 KB)

__device__ __forceinline__ void fma8(float (&o)[8], float p, const float4& a, const float4& b) {
    o[0] += p * a.x; o[1] += p * a.y; o[2] += p * a.z; o[3] += p * a.w;
    o[4] += p * b.x; o[5] += p * b.y; o[6] += p * b.z; o[7] += p * b.w;
}

// ---------------------------------------------------------------------------
// 1) landmark means
// ---------------------------------------------------------------------------
__global__ __launch_bounds__(64) void k_landmarks(
    const float* __restrict__ q, const float* __restrict__ k,
    float* __restrict__ ql, float* __restrict__ kl)
{
    int mi = blockIdx.x & 255;
    int bh = blockIdx.x >> 8;
    const float* src = blockIdx.y ? k : q;
    float*       dst = blockIdx.y ? kl : ql;
    int t = threadIdx.x;
    const float* s = src + ((size_t)bh * N_SEQ + (size_t)mi * 32) * DHEAD;
    float acc = 0.f;
    #pragma unroll
    for (int j = 0; j < 32; ++j) acc += s[j * DHEAD + t];
    dst[((size_t)bh * MLAND + mi) * DHEAD + t] = acc * (1.f / 32.f);
}

// ---------------------------------------------------------------------------
// 2) attn2 = softmax(ql @ kl^T) rowwise
// ---------------------------------------------------------------------------
__global__ __launch_bounds__(256) void k_sim2_softmax(
    const float* __restrict__ ql, const float* __restrict__ kl,
    float* __restrict__ attn2)
{
    int bh = blockIdx.x >> 8;
    int i  = blockIdx.x & 255;
    int t  = threadIdx.x;
    __shared__ float qrow[DHEAD];
    __shared__ float wred[8];
    if (t < DHEAD) qrow[t] = ql[((size_t)bh * MLAND + i) * DHEAD + t];
    __syncthreads();
    const float* krow = kl + ((size_t)bh * MLAND + t) * DHEAD;
    float s = 0.f;
    #pragma unroll
    for (int kk = 0; kk < DHEAD; kk += 4) {
        float4 k4 = *(const float4*)(krow + kk);
        s += qrow[kk] * k4.x + qrow[kk + 1] * k4.y + qrow[kk + 2] * k4.z + qrow[kk + 3] * k4.w;
    }
    float m = s;
    #pragma unroll
    for (int o = 32; o > 0; o >>= 1) m = fmaxf(m, __shfl_xor(m, o, 64));
    int wave = t >> 6, lane = t & 63;
    if (lane == 0) wred[wave] = m;
    __syncthreads();
    float bm = fmaxf(fmaxf(wred[0], wred[1]), fmaxf(wred[2], wred[3]));
    float e = __expf(s - bm);
    float sum = e;
    #pragma unroll
    for (int o = 32; o > 0; o >>= 1) sum += __shfl_xor(sum, o, 64);
    if (lane == 0) wred[4 + wave] = sum;
    __syncthreads();
    float bs = wred[4] + wred[5] + wred[6] + wred[7];
    attn2[((size_t)bh * MLAND + i) * MLAND + t] = e / bs;
}

// ---------------------------------------------------------------------------
// 3a) global max of row-sums and col-sums of attn2
// ---------------------------------------------------------------------------
__global__ __launch_bounds__(256) void k_scale_reduce(
    const float* __restrict__ x, float* __restrict__ scl)
{
    int bh = blockIdx.x, t = threadIdx.x;
    const float* xb = x + (size_t)bh * MLAND * MLAND;
    float colsum = 0.f, rowsum = 0.f;
    for (int i = 0; i < MLAND; ++i) colsum += xb[(size_t)i * MLAND + t];
    for (int j = 0; j < MLAND; ++j) rowsum += xb[(size_t)t * MLAND + j];
    __shared__ float red[256];
    red[t] = rowsum;
    __syncthreads();
    for (int o = 128; o > 0; o >>= 1) {
        if (t < o) red[t] = fmaxf(red[t], red[t + o]);
        __syncthreads();
    }
    if (t == 0) atomicMax((unsigned int*)&scl[0], __float_as_uint(red[0]));
    __syncthreads();
    red[t] = colsum;
    __syncthreads();
    for (int o = 128; o > 0; o >>= 1) {
        if (t < o) red[t] = fmaxf(red[t], red[t + o]);
        __syncthreads();
    }
    if (t == 0) atomicMax((unsigned int*)&scl[1], __float_as_uint(red[0]));
}

// ---------------------------------------------------------------------------
// 3b) z0 = attn2^T / (scl[0]*scl[1])
// ---------------------------------------------------------------------------
__global__ __launch_bounds__(256) void k_zinit(
    const float* __restrict__ x, float* __restrict__ z,
    const float* __restrict__ scl)
{
    __shared__ float tile[32][33];
    int bh = blockIdx.z;
    int i0 = blockIdx.y * 32, j0 = blockIdx.x * 32;
    int t = threadIdx.x;
    int lx = t & 31, ly = t >> 5;
    const float* xb = x + (size_t)bh * MLAND * MLAND;
    float*       zb = z + (size_t)bh * MLAND * MLAND;
    #pragma unroll
    for (int p = 0; p < 4; ++p)
        tile[ly + 8 * p][lx] = xb[(size_t)(i0 + ly + 8 * p) * MLAND + j0 + lx];
    __syncthreads();
    float inv = 1.0f / (scl[0] * scl[1]);
    #pragma unroll
    for (int p = 0; p < 4; ++p)
        zb[(size_t)(j0 + ly + 8 * p) * MLAND + i0 + lx] = tile[lx][ly + 8 * p] * inv;
}

// ---------------------------------------------------------------------------
// 4) persistent pinv mega-kernel: 24 GEMM phases + final W GEMM, one dispatch.
//    grid 256 blocks (1/CU, co-resident), atomic grid barrier between phases.
// ---------------------------------------------------------------------------
__device__ __forceinline__ void grid_barrier(int* cnt, int* gen) {
    __syncthreads();
    if (threadIdx.x == 0) {
        __threadfence();                       // release: phase writes visible
        int g = atomicAdd(gen, 0);
        if (atomicAdd(cnt, 1) == 255) {
            atomicExch(cnt, 0);
            __threadfence();
            atomicAdd(gen, 1);
        } else {
            while (atomicAdd(gen, 0) == g) __builtin_amdgcn_s_sleep(2);
        }
        __threadfence();                       // acquire
    }
    __syncthreads();
}

// C[64x64 tile] = outscale * (A @ (diag*I + bscale*B)); A:[256][256], B:[256][N]
__device__ __forceinline__ void gemm64_tile(
    const float* A, const float* B, float* C, int N,
    int m0, int n0, float diag, float bscale, float outscale,
    float* sm, int t)
{
    float acc[4][4] = {};
    int tx = t & 15, ty = t >> 4;
    float* As = sm;
    float* Bs = sm + 64 * 68;
    for (int kc = 0; kc < 256; kc += 64) {
        __syncthreads();
        {   // As[kk][m] transposed
            int m = t & 63, kq = t >> 6;
            const float* src = A + (size_t)(m0 + m) * 256 + kc + kq * 16;
            #pragma unroll
            for (int o = 0; o < 16; o += 4) {
                float4 a = *(const float4*)(src + o);
                As[(kq * 16 + o + 0) * 68 + m] = a.x;
                As[(kq * 16 + o + 1) * 68 + m] = a.y;
                As[(kq * 16 + o + 2) * 68 + m] = a.z;
                As[(kq * 16 + o + 3) * 68 + m] = a.w;
            }
        }
        {   // Bs[kk][n] with fused affine
            int kk = t & 63, nq = t >> 6;
            int gk = kc + kk;
            const float* src = B + (size_t)gk * N + n0 + nq * 16;
            #pragma unroll
            for (int o = 0; o < 16; o += 4) {
                float4 bv = *(const float4*)(src + o);
                float r[4] = {bv.x, bv.y, bv.z, bv.w};
                #pragma unroll
                for (int u = 0; u < 4; ++u) {
                    float val = bscale * r[u];
                    if (gk == n0 + nq * 16 + o + u) val += diag;
                    r[u] = val;
                }
                *(float4*)&Bs[kk * 68 + nq * 16 + o] = make_float4(r[0], r[1], r[2], r[3]);
            }
        }
        __syncthreads();
        #pragma unroll 4
        for (int kk = 0; kk < 64; ++kk) {
            float4 a4 = *(const float4*)&As[kk * 68 + ty * 4];
            float4 b4 = *(const float4*)&Bs[kk * 68 + tx * 4];
            float a[4] = {a4.x, a4.y, a4.z, a4.w};
            #pragma unroll
            for (int i = 0; i < 4; ++i) {
                acc[i][0] += a[i] * b4.x; acc[i][1] += a[i] * b4.y;
                acc[i][2] += a[i] * b4.z; acc[i][3] += a[i] * b4.w;
            }
        }
    }
    #pragma unroll
    for (int i = 0; i < 4; ++i) {
        float* dst = C + (size_t)(m0 + ty * 4 + i) * N + n0 + tx * 4;
        *(float4*)dst = make_float4(acc[i][0] * outscale, acc[i][1] * outscale,
                                    acc[i][2] * outscale, acc[i][3] * outscale);
    }
}

__global__ __launch_bounds__(256) void k_pinv_mega(
    const float* x, float* z, float* z2, float* xz, float* t2, float* t3,
    const float* kv, float* W, int* cnt, int* gen)
{
    __shared__ __align__(16) float sm[2 * 64 * 68];
    int b = blockIdx.x, t = threadIdx.x;
    int bh = b >> 4, mi = (b >> 2) & 3, ni = b & 3;
    size_t mm = (size_t)bh * 65536;
    for (int p = 0; p < 24; ++p) {
        int step = p & 3, it = p >> 2;
        float* zc = (it & 1) ? z2 : z;
        float* zn = (it & 1) ? z  : z2;
        const float *A, *B; float* C; float dg, bsc, osc;
        if (step == 0)      { A = x;  B = zc; C = xz; dg = 0.f;  bsc =  1.f; osc = 1.f; }
        else if (step == 1) { A = xz; B = xz; C = t2; dg = 7.f;  bsc = -1.f; osc = 1.f; }
        else if (step == 2) { A = xz; B = t2; C = t3; dg = 15.f; bsc = -1.f; osc = 1.f; }
        else                { A = zc; B = t3; C = zn; dg = 13.f; bsc = -1.f; osc = 0.25f; }
        gemm64_tile(A + mm, B + mm, C + mm, 256, mi * 64, ni * 64, dg, bsc, osc, sm, t);
        grid_barrier(cnt, gen);
    }
    // W = z_final @ kv ; after 6 swaps z_final == z. Blocks 0..63 active.
    if (b < 64) {
        int bh2 = b >> 2, mi2 = b & 3;
        gemm64_tile(z + (size_t)bh2 * 65536, kv + (size_t)bh2 * 16384,
                    W + (size_t)bh2 * 16384, 64, mi2 * 64, 0, 0.f, 1.f, 1.f, sm, t);
    }
}

// ---------------------------------------------------------------------------
// 5a) attn3 flash partial: 128 landmarks/block, 512-key split.
//     grid (16 splits, 2 halves, NBH), block 256, 4x8 micro/lane. 2 blk/CU.
// ---------------------------------------------------------------------------
__global__ __launch_bounds__(256, 2) void k_attn3_partial(
    const float* __restrict__ ql, const float* __restrict__ k,
    const float* __restrict__ v, float* __restrict__ pO,
    float* __restrict__ pm, float* __restrict__ pl)
{
    __shared__ __align__(16) float smem[FL_SMEM];
    int sp = blockIdx.x;
    int m0 = blockIdx.y * 128;
    int bh = blockIdx.z;
    int t = threadIdx.x;
    int wave = t >> 6, lane = t & 63;
    int ly = lane >> 3, lx = lane & 7;
    int rb = wave * 32 + ly * 4;     // lane's first row of 128

    {   // stage 128 q-rows transposed (each thread half a row)
        int m = t >> 1, k0 = (t & 1) * 32;
        const float* src = ql + ((size_t)bh * MLAND + m0 + m) * DHEAD + k0;
        #pragma unroll
        for (int kk = 0; kk < 32; kk += 4) {
            float4 a = *(const float4*)(src + kk);
            smem[(k0 + kk + 0) * QT_STRIDE + m] = a.x;
            smem[(k0 + kk + 1) * QT_STRIDE + m] = a.y;
            smem[(k0 + kk + 2) * QT_STRIDE + m] = a.z;
            smem[(k0 + kk + 3) * QT_STRIDE + m] = a.w;
        }
    }

    float S[4][8], O[4][8] = {};
    float M[4], L[4];
    #pragma unroll
    for (int i = 0; i < 4; ++i) { M[i] = -1e30f; L[i] = 0.f; }

    const float* kb = k + (size_t)bh * N_SEQ * DHEAD;
    const float* vb = v + (size_t)bh * N_SEQ * DHEAD;

    for (int cc = 0; cc < 8; ++cc) {
        int c0 = sp * 512 + cc * 64;
        __syncthreads();
        {   // kp = K^T chunk [kk][j]
            int j = t & 63, kq = t >> 6;
            const float* src = kb + (size_t)(c0 + j) * DHEAD + kq * 16;
            #pragma unroll
            for (int o = 0; o < 16; o += 4) {
                float4 a = *(const float4*)(src + o);
                smem[KP_OFF + (kq * 16 + o + 0) * 68 + j] = a.x;
                smem[KP_OFF + (kq * 16 + o + 1) * 68 + j] = a.y;
                smem[KP_OFF + (kq * 16 + o + 2) * 68 + j] = a.z;
                smem[KP_OFF + (kq * 16 + o + 3) * 68 + j] = a.w;
            }
        }
        {   // wc = V chunk natural [j][d]
            int j = t & 63, dq = t >> 6;
            const float* src = vb + (size_t)(c0 + j) * DHEAD + dq * 16;
            #pragma unroll
            for (int o = 0; o < 16; o += 4)
                *(float4*)&smem[WC_OFF + j * 68 + dq * 16 + o] = *(const float4*)(src + o);
        }
        __syncthreads();

        #pragma unroll
        for (int i = 0; i < 4; ++i)
            #pragma unroll
            for (int j = 0; j < 8; ++j) S[i][j] = 0.f;
        #pragma unroll 4
        for (int kk = 0; kk < DHEAD; ++kk) {
            float4 a4 = *(const float4*)&smem[kk * QT_STRIDE + rb];
            float4 b0 = *(const float4*)&smem[KP_OFF + kk * 68 + lx * 8];
            float4 b1 = *(const float4*)&smem[KP_OFF + kk * 68 + lx * 8 + 4];
            float av[4] = {a4.x, a4.y, a4.z, a4.w};
            #pragma unroll
            for (int i = 0; i < 4; ++i) fma8(S[i], av[i], b0, b1);
        }

        #pragma unroll
        for (int i = 0; i < 4; ++i) {
            float mv = S[i][0];
            #pragma unroll
            for (int j = 1; j < 8; ++j) mv = fmaxf(mv, S[i][j]);
            mv = fmaxf(mv, __shfl_xor(mv, 4, 8));
            mv = fmaxf(mv, __shfl_xor(mv, 2, 8));
            mv = fmaxf(mv, __shfl_xor(mv, 1, 8));
            float nM = fmaxf(M[i], mv);
            float alpha = __expf(M[i] - nM);
            M[i] = nM;
            float rs = 0.f;
            #pragma unroll
            for (int j = 0; j < 8; ++j) { S[i][j] = __expf(S[i][j] - nM); rs += S[i][j]; }
            rs += __shfl_xor(rs, 4, 8);
            rs += __shfl_xor(rs, 2, 8);
            rs += __shfl_xor(rs, 1, 8);
            L[i] = L[i] * alpha + rs;
            #pragma unroll
            for (int j = 0; j < 8; ++j) O[i][j] *= alpha;
        }

        #pragma unroll 2
        for (int lsrc = 0; lsrc < 8; ++lsrc) {
            #pragma unroll
            for (int jq = 0; jq < 8; ++jq) {
                int j = lsrc * 8 + jq;
                float4 v0 = *(const float4*)&smem[WC_OFF + j * 68 + lx * 8];
                float4 v1 = *(const float4*)&smem[WC_OFF + j * 68 + lx * 8 + 4];
                #pragma unroll
                for (int i = 0; i < 4; ++i) {
                    float p = __shfl(S[i][jq], lsrc, 8);
                    fma8(O[i], p, v0, v1);
                }
            }
        }
    }

    int base = (bh * 16 + sp) * MLAND + m0;
    #pragma unroll
    for (int i = 0; i < 4; ++i) {
        int r = rb + i;
        if (lx == 0) { pm[base + r] = M[i]; pl[base + r] = L[i]; }
        float* dst = pO + (size_t)(base + r) * DHEAD + lx * 8;
        *(float4*)dst = make_float4(O[i][0], O[i][1], O[i][2], O[i][3]);
        *(float4*)(dst + 4) = make_float4(O[i][4], O[i][5], O[i][6], O[i][7]);
    }
}

// ---------------------------------------------------------------------------
// 5b) combine 16 splits -> kv
// ---------------------------------------------------------------------------
__global__ __launch_bounds__(64) void k_attn3_combine(
    const float* __restrict__ pO, const float* __restrict__ pm,
    const float* __restrict__ pl, float* __restrict__ kv)
{
    int bh = blockIdx.x >> 8;
    int m  = blockIdx.x & 255;
    int d  = threadIdx.x;
    float M = -1e30f;
    #pragma unroll
    for (int s = 0; s < 16; ++s) M = fmaxf(M, pm[(bh * 16 + s) * MLAND + m]);
    float L = 0.f, O = 0.f;
    #pragma unroll
    for (int s = 0; s < 16; ++s) {
        int base = (bh * 16 + s) * MLAND + m;
        float w = __expf(pm[base] - M);
        L += pl[base] * w;
        O += w * pO[(size_t)base * DHEAD + d];
    }
    kv[((size_t)bh * MLAND + m) * DHEAD + d] = O / L;
}

// ---------------------------------------------------------------------------
// 6) out = softmax(q @ kl^T) @ W + conv33(v). 128 q-rows/block, 4x8/lane.
//    grid (64, NBH), block 256, 2 blk/CU.
// ---------------------------------------------------------------------------
__global__ __launch_bounds__(256, 2) void k_attn1_out(
    const float* __restrict__ q, const float* __restrict__ kl,
    const float* __restrict__ W, const float* __restrict__ v,
    const float* __restrict__ cw, float* __restrict__ out)
{
    __shared__ __align__(16) float smem[FL_SMEM];
    __shared__ float wgt[33];
    int bh = blockIdx.y;
    int r0 = blockIdx.x * 128;
    int t = threadIdx.x;
    int wave = t >> 6, lane = t & 63;
    int ly = lane >> 3, lx = lane & 7;
    int rb = wave * 32 + ly * 4;

    if (t < 33) wgt[t] = cw[(bh & 7) * 33 + t];
    {   // stage 128 q-rows transposed
        int m = t >> 1, k0 = (t & 1) * 32;
        const float* src = q + ((size_t)bh * N_SEQ + r0 + m) * DHEAD + k0;
        #pragma unroll
        for (int kk = 0; kk < 32; kk += 4) {
            float4 a = *(const float4*)(src + kk);
            smem[(k0 + kk + 0) * QT_STRIDE + m] = a.x;
            smem[(k0 + kk + 1) * QT_STRIDE + m] = a.y;
            smem[(k0 + kk + 2) * QT_STRIDE + m] = a.z;
            smem[(k0 + kk + 3) * QT_STRIDE + m] = a.w;
        }
    }

    float S[4][8], O[4][8] = {};
    float M[4], L[4];
    #pragma unroll
    for (int i = 0; i < 4; ++i) { M[i] = -1e30f; L[i] = 0.f; }

    for (int mc = 0; mc < 4; ++mc) {
        __syncthreads();
        {   // kp = kl^T chunk
            int j = t & 63, kq = t >> 6;
            const float* src = kl + ((size_t)bh * MLAND + mc * 64 + j) * DHEAD + kq * 16;
            #pragma unroll
            for (int o = 0; o < 16; o += 4) {
                float4 a = *(const float4*)(src + o);
                smem[KP_OFF + (kq * 16 + o + 0) * 68 + j] = a.x;
                smem[KP_OFF + (kq * 16 + o + 1) * 68 + j] = a.y;
                smem[KP_OFF + (kq * 16 + o + 2) * 68 + j] = a.z;
                smem[KP_OFF + (kq * 16 + o + 3) * 68 + j] = a.w;
            }
        }
        {   // wc = W chunk natural
            int j = t & 63, dq = t >> 6;
            const float* src = W + ((size_t)bh * MLAND + mc * 64 + j) * DHEAD + dq * 16;
            #pragma unroll
            for (int o = 0; o < 16; o += 4)
                *(float4*)&smem[WC_OFF + j * 68 + dq * 16 + o] = *(const float4*)(src + o);
        }
        __syncthreads();

        #pragma unroll
        for (int i = 0; i < 4; ++i)
            #pragma unroll
            for (int j = 0; j < 8; ++j) S[i][j] = 0.f;
        #pragma unroll 4
        for (int kk = 0; kk < DHEAD; ++kk) {
            float4 a4 = *(const float4*)&smem[kk * QT_STRIDE + rb];
            float4 b0 = *(const float4*)&smem[KP_OFF + kk * 68 + lx * 8];
            float4 b1 = *(const float4*)&smem[KP_OFF + kk * 68 + lx * 8 + 4];
            float av[4] = {a4.x, a4.y, a4.z, a4.w};
            #pragma unroll
            for (int i = 0; i < 4; ++i) fma8(S[i], av[i], b0, b1);
        }

        #pragma unroll
        for (int i = 0; i < 4; ++i) {
            float mv = S[i][0];
            #pragma unroll
            for (int j = 1; j < 8; ++j) mv = fmaxf(mv, S[i][j]);
            mv = fmaxf(mv, __shfl_xor(mv, 4, 8));
            mv = fmaxf(mv, __shfl_xor(mv, 2, 8));
            mv = fmaxf(mv, __shfl_xor(mv, 1, 8));
            float nM = fmaxf(M[i], mv);
            float alpha = __expf(M[i] - nM);
            M[i] = nM;
            float rs = 0.f;
            #pragma unroll
            for (int j = 0; j < 8; ++j) { S[i][j] = __expf(S[i][j] - nM); rs += S[i][j]; }
            rs += __shfl_xor(rs, 4, 8);
            rs += __shfl_xor(rs, 2, 8);
            rs += __shfl_xor(rs, 1, 8);
            L[i] = L[i] * alpha + rs;
            #pragma unroll
            for (int j = 0; j < 8; ++j) O[i][j] *= alpha;
        }

        #pragma unroll 2
        for (int lsrc = 0; lsrc < 8; ++lsrc) {
            #pragma unroll
            for (int jq = 0; jq < 8; ++jq) {
                int j = lsrc * 8 + jq;
                float4 v0 = *(const float4*)&smem[WC_OFF + j * 68 + lx * 8];
                float4 v1 = *(const float4*)&smem[WC_OFF + j * 68 + lx * 8 + 4];
                #pragma unroll
                for (int i = 0; i < 4; ++i) {
                    float p = __shfl(S[i][jq], lsrc, 8);
                    fma8(O[i], p, v0, v1);
                }
            }
        }
    }

    float inv[4];
    #pragma unroll
    for (int i = 0; i < 4; ++i) inv[i] = 1.0f / L[i];

    // conv: stage v rows [r0-16, r0+144) at smem base, stride 68
    __syncthreads();
    for (int rr = t; rr < 160; rr += 256) {
        int gr = r0 - 16 + rr;
        bool ok = (gr >= 0) && (gr < N_SEQ);
        const float* src = v + ((size_t)bh * N_SEQ + gr) * DHEAD;
        #pragma unroll
        for (int c = 0; c < 64; c += 4) {
            float4 val = ok ? *(const float4*)(src + c) : make_float4(0.f, 0.f, 0.f, 0.f);
            *(float4*)&smem[rr * 68 + c] = val;
        }
    }
    __syncthreads();

    float res[4][8] = {};
    #pragma unroll
    for (int w = 0; w < 36; ++w) {
        float4 va = *(const float4*)&smem[(rb + w) * 68 + lx * 8];
        float4 vb4 = *(const float4*)&smem[(rb + w) * 68 + lx * 8 + 4];
        #pragma unroll
        for (int i = 0; i < 4; ++i) {
            if (w - i >= 0 && w - i <= 32) {
                float wv = wgt[w - i];
                fma8(res[i], wv, va, vb4);
            }
        }
    }

    #pragma unroll
    for (int i = 0; i < 4; ++i) {
        float* dst = out + ((size_t)bh * N_SEQ + r0 + rb + i) * DHEAD + lx * 8;
        *(float4*)dst = make_float4(O[i][0] * inv[i] + res[i][0], O[i][1] * inv[i] + res[i][1],
                                    O[i][2] * inv[i] + res[i][2], O[i][3] * inv[i] + res[i][3]);
        *(float4*)(dst + 4) = make_float4(O[i][4] * inv[i] + res[i][4], O[i][5] * inv[i] + res[i][5],
                                          O[i][6] * inv[i] + res[i][6], O[i][7] * inv[i] + res[i][7]);
    }
}

// ---------------------------------------------------------------------------
// launch
// ---------------------------------------------------------------------------
extern "C" void kernel_launch(void* const* d_in, const int* in_sizes, int n_in,
                              void* d_out, int out_size, void* d_ws, size_t ws_size,
                              hipStream_t stream)
{
    (void)in_sizes; (void)n_in; (void)out_size; (void)ws_size;
    const float* q  = (const float*)d_in[0];
    const float* k  = (const float*)d_in[1];
    const float* v  = (const float*)d_in[2];
    const float* cw = (const float*)d_in[3];
    float* out = (float*)d_out;
    float* ws  = (float*)d_ws;

    const size_t LM = (size_t)NBH * MLAND * DHEAD;   // 262144 floats
    const size_t MM = (size_t)NBH * MLAND * MLAND;   // 1048576 floats
    float* ql  = ws;
    float* kl  = ql  + LM;
    float* x   = kl  + LM;   // attn2
    float* z   = x   + MM;
    float* z2  = z   + MM;
    float* xz  = z2  + MM;
    float* t2  = xz  + MM;
    float* t3  = t2  + MM;
    float* kv  = t3  + MM;
    float* W   = kv  + LM;
    float* scl = W   + LM;   // [0,1]=scales; [4,5]=barrier cnt/gen (ints)
    float* pm  = scl + 16;
    float* pl  = pm + (size_t)NBH * 16 * MLAND;
    int*   bar = (int*)(scl + 4);

    // attn3 partials: pO spans z2..t3 (4*MM floats), dead before pinv.
    float* pO = z2;

    hipMemsetAsync(scl, 0, 32, stream);   // scales + barrier counters

    k_landmarks<<<dim3(NBH * MLAND, 2), 64, 0, stream>>>(q, k, ql, kl);
    k_sim2_softmax<<<NBH * MLAND, 256, 0, stream>>>(ql, kl, x);
    k_scale_reduce<<<NBH, 256, 0, stream>>>(x, scl);
    k_zinit<<<dim3(8, 8, NBH), 256, 0, stream>>>(x, z, scl);

    k_attn3_partial<<<dim3(16, 2, NBH), 256, 0, stream>>>(ql, k, v, pO, pm, pl);
    k_attn3_combine<<<NBH * MLAND, 64, 0, stream>>>(pO, pm, pl, kv);

    // Moore-Penrose (6 iters x 4 gemms) + W = z@kv, one persistent dispatch
    k_pinv_mega<<<256, 256, 0, stream>>>(x, z, z2, xz, t2, t3, kv, W, bar, bar + 1);

    k_attn1_out<<<dim3(64, NBH), 256, 0, stream>>>(q, kl, W, v, cw, out);
}

// Round 6
// 943.160 us; speedup vs baseline: 1.5618x; 1.5618x over previous
//
#include <hip/hip_runtime.h>

// ---------------------------------------------------------------------------
// Nystrom attention, fp32. b=2,h=8,n=8192,d=64, m=256 landmarks, conv33.
// Round 6: pinv back to per-GEMM dispatches with 512-thread (8-wave) blocks.
// ---------------------------------------------------------------------------

#define N_SEQ 8192
#define NBH   16
#define MLAND 256
#define DHEAD 64

// flash kernels' shared layout (floats): Qt [64][132] | KP [64][68] | WC [64][68]
#define QT_STRIDE 132
#define KP_OFF    8448           // 64*132
#define WC_OFF    12800          // + 64*68
#define FL_SMEM   17152          // + 64*68  (68.6 KB)

__device__ __forceinline__ void fma8(float (&o)[8], float p, const float4& a, const float4& b) {
    o[0] += p * a.x; o[1] += p * a.y; o[2] += p * a.z; o[3] += p * a.w;
    o[4] += p * b.x; o[5] += p * b.y; o[6] += p * b.z; o[7] += p * b.w;
}

// ---------------------------------------------------------------------------
// 1) landmark means
// ---------------------------------------------------------------------------
__global__ __launch_bounds__(64) void k_landmarks(
    const float* __restrict__ q, const float* __restrict__ k,
    float* __restrict__ ql, float* __restrict__ kl)
{
    int mi = blockIdx.x & 255;
    int bh = blockIdx.x >> 8;
    const float* src = blockIdx.y ? k : q;
    float*       dst = blockIdx.y ? kl : ql;
    int t = threadIdx.x;
    const float* s = src + ((size_t)bh * N_SEQ + (size_t)mi * 32) * DHEAD;
    float acc = 0.f;
    #pragma unroll
    for (int j = 0; j < 32; ++j) acc += s[j * DHEAD + t];
    dst[((size_t)bh * MLAND + mi) * DHEAD + t] = acc * (1.f / 32.f);
}

// ---------------------------------------------------------------------------
// 2) attn2 = softmax(ql @ kl^T) rowwise
// ---------------------------------------------------------------------------
__global__ __launch_bounds__(256) void k_sim2_softmax(
    const float* __restrict__ ql, const float* __restrict__ kl,
    float* __restrict__ attn2)
{
    int bh = blockIdx.x >> 8;
    int i  = blockIdx.x & 255;
    int t  = threadIdx.x;
    __shared__ float qrow[DHEAD];
    __shared__ float wred[8];
    if (t < DHEAD) qrow[t] = ql[((size_t)bh * MLAND + i) * DHEAD + t];
    __syncthreads();
    const float* krow = kl + ((size_t)bh * MLAND + t) * DHEAD;
    float s = 0.f;
    #pragma unroll
    for (int kk = 0; kk < DHEAD; kk += 4) {
        float4 k4 = *(const float4*)(krow + kk);
        s += qrow[kk] * k4.x + qrow[kk + 1] * k4.y + qrow[kk + 2] * k4.z + qrow[kk + 3] * k4.w;
    }
    float m = s;
    #pragma unroll
    for (int o = 32; o > 0; o >>= 1) m = fmaxf(m, __shfl_xor(m, o, 64));
    int wave = t >> 6, lane = t & 63;
    if (lane == 0) wred[wave] = m;
    __syncthreads();
    float bm = fmaxf(fmaxf(wred[0], wred[1]), fmaxf(wred[2], wred[3]));
    float e = __expf(s - bm);
    float sum = e;
    #pragma unroll
    for (int o = 32; o > 0; o >>= 1) sum += __shfl_xor(sum, o, 64);
    if (lane == 0) wred[4 + wave] = sum;
    __syncthreads();
    float bs = wred[4] + wred[5] + wred[6] + wred[7];
    attn2[((size_t)bh * MLAND + i) * MLAND + t] = e / bs;
}

// ---------------------------------------------------------------------------
// 3a) global max of row-sums and col-sums of attn2
// ---------------------------------------------------------------------------
__global__ __launch_bounds__(256) void k_scale_reduce(
    const float* __restrict__ x, float* __restrict__ scl)
{
    int bh = blockIdx.x, t = threadIdx.x;
    const float* xb = x + (size_t)bh * MLAND * MLAND;
    float colsum = 0.f, rowsum = 0.f;
    for (int i = 0; i < MLAND; ++i) colsum += xb[(size_t)i * MLAND + t];
    for (int j = 0; j < MLAND; ++j) rowsum += xb[(size_t)t * MLAND + j];
    __shared__ float red[256];
    red[t] = rowsum;
    __syncthreads();
    for (int o = 128; o > 0; o >>= 1) {
        if (t < o) red[t] = fmaxf(red[t], red[t + o]);
        __syncthreads();
    }
    if (t == 0) atomicMax((unsigned int*)&scl[0], __float_as_uint(red[0]));
    __syncthreads();
    red[t] = colsum;
    __syncthreads();
    for (int o = 128; o > 0; o >>= 1) {
        if (t < o) red[t] = fmaxf(red[t], red[t + o]);
        __syncthreads();
    }
    if (t == 0) atomicMax((unsigned int*)&scl[1], __float_as_uint(red[0]));
}

// ---------------------------------------------------------------------------
// 3b) z0 = attn2^T / (scl[0]*scl[1])
// ---------------------------------------------------------------------------
__global__ __launch_bounds__(256) void k_zinit(
    const float* __restrict__ x, float* __restrict__ z,
    const float* __restrict__ scl)
{
    __shared__ float tile[32][33];
    int bh = blockIdx.z;
    int i0 = blockIdx.y * 32, j0 = blockIdx.x * 32;
    int t = threadIdx.x;
    int lx = t & 31, ly = t >> 5;
    const float* xb = x + (size_t)bh * MLAND * MLAND;
    float*       zb = z + (size_t)bh * MLAND * MLAND;
    #pragma unroll
    for (int p = 0; p < 4; ++p)
        tile[ly + 8 * p][lx] = xb[(size_t)(i0 + ly + 8 * p) * MLAND + j0 + lx];
    __syncthreads();
    float inv = 1.0f / (scl[0] * scl[1]);
    #pragma unroll
    for (int p = 0; p < 4; ++p)
        zb[(size_t)(j0 + ly + 8 * p) * MLAND + i0 + lx] = tile[lx][ly + 8 * p] * inv;
}

// ---------------------------------------------------------------------------
// 4) batched C = outscale * (A @ (diag*I + bscale*B)); M=K=256 fixed, N param.
//    64x64 tile, 512 threads (8 waves -> 2/SIMD), 2x4 micro/lane.
// ---------------------------------------------------------------------------
__global__ __launch_bounds__(512) void k_bmm512(
    const float* __restrict__ A, const float* __restrict__ B, float* __restrict__ C,
    int N, float diag, float bscale, float outscale)
{
    __shared__ __align__(16) float As[64 * 68];
    __shared__ __align__(16) float Bs[64 * 68];
    int bh = blockIdx.z;
    const float* Ab = A + (size_t)bh * 65536;
    const float* Bb = B + (size_t)bh * 256 * N;
    float*       Cb = C + (size_t)bh * 256 * N;
    int m0 = blockIdx.y * 64, n0 = blockIdx.x * 64;
    int t = threadIdx.x;
    int ty = t >> 4, tx = t & 15;            // 32 x 16
    float acc[2][4] = {};
    for (int kc = 0; kc < 256; kc += 64) {
        __syncthreads();
        {   // stage A[m][kk] -> As[kk][m] (8 floats per thread)
            int m = t & 63, kq = t >> 6;     // kq 0..7
            const float* src = Ab + (size_t)(m0 + m) * 256 + kc + kq * 8;
            float4 a = *(const float4*)src;
            float4 b = *(const float4*)(src + 4);
            As[(kq * 8 + 0) * 68 + m] = a.x; As[(kq * 8 + 1) * 68 + m] = a.y;
            As[(kq * 8 + 2) * 68 + m] = a.z; As[(kq * 8 + 3) * 68 + m] = a.w;
            As[(kq * 8 + 4) * 68 + m] = b.x; As[(kq * 8 + 5) * 68 + m] = b.y;
            As[(kq * 8 + 6) * 68 + m] = b.z; As[(kq * 8 + 7) * 68 + m] = b.w;
        }
        {   // stage B[kk][n] natural, fused affine (diag*I + bscale*B)
            int kk = t & 63, nq = t >> 6;    // 8 cols per thread
            int gk = kc + kk;
            const float* src = Bb + (size_t)gk * N + n0 + nq * 8;
            float4 b0 = *(const float4*)src;
            float4 b1 = *(const float4*)(src + 4);
            float r[8] = {b0.x, b0.y, b0.z, b0.w, b1.x, b1.y, b1.z, b1.w};
            #pragma unroll
            for (int u = 0; u < 8; ++u) {
                float val = bscale * r[u];
                if (gk == n0 + nq * 8 + u) val += diag;
                r[u] = val;
            }
            *(float4*)&Bs[kk * 68 + nq * 8]     = make_float4(r[0], r[1], r[2], r[3]);
            *(float4*)&Bs[kk * 68 + nq * 8 + 4] = make_float4(r[4], r[5], r[6], r[7]);
        }
        __syncthreads();
        #pragma unroll 8
        for (int kk = 0; kk < 64; ++kk) {
            float2 a2 = *(const float2*)&As[kk * 68 + ty * 2];
            float4 b4 = *(const float4*)&Bs[kk * 68 + tx * 4];
            acc[0][0] += a2.x * b4.x; acc[0][1] += a2.x * b4.y;
            acc[0][2] += a2.x * b4.z; acc[0][3] += a2.x * b4.w;
            acc[1][0] += a2.y * b4.x; acc[1][1] += a2.y * b4.y;
            acc[1][2] += a2.y * b4.z; acc[1][3] += a2.y * b4.w;
        }
    }
    #pragma unroll
    for (int i = 0; i < 2; ++i) {
        float* dst = Cb + (size_t)(m0 + ty * 2 + i) * N + n0 + tx * 4;
        *(float4*)dst = make_float4(acc[i][0] * outscale, acc[i][1] * outscale,
                                    acc[i][2] * outscale, acc[i][3] * outscale);
    }
}

// ---------------------------------------------------------------------------
// 5a) attn3 flash partial: 128 landmarks/block, 512-key split.
//     grid (16 splits, 2 halves, NBH), block 256, 4x8 micro/lane. 2 blk/CU.
// ---------------------------------------------------------------------------
__global__ __launch_bounds__(256, 2) void k_attn3_partial(
    const float* __restrict__ ql, const float* __restrict__ k,
    const float* __restrict__ v, float* __restrict__ pO,
    float* __restrict__ pm, float* __restrict__ pl)
{
    __shared__ __align__(16) float smem[FL_SMEM];
    int sp = blockIdx.x;
    int m0 = blockIdx.y * 128;
    int bh = blockIdx.z;
    int t = threadIdx.x;
    int wave = t >> 6, lane = t & 63;
    int ly = lane >> 3, lx = lane & 7;
    int rb = wave * 32 + ly * 4;     // lane's first row of 128

    {   // stage 128 q-rows transposed (each thread half a row)
        int m = t >> 1, k0 = (t & 1) * 32;
        const float* src = ql + ((size_t)bh * MLAND + m0 + m) * DHEAD + k0;
        #pragma unroll
        for (int kk = 0; kk < 32; kk += 4) {
            float4 a = *(const float4*)(src + kk);
            smem[(k0 + kk + 0) * QT_STRIDE + m] = a.x;
            smem[(k0 + kk + 1) * QT_STRIDE + m] = a.y;
            smem[(k0 + kk + 2) * QT_STRIDE + m] = a.z;
            smem[(k0 + kk + 3) * QT_STRIDE + m] = a.w;
        }
    }

    float S[4][8], O[4][8] = {};
    float M[4], L[4];
    #pragma unroll
    for (int i = 0; i < 4; ++i) { M[i] = -1e30f; L[i] = 0.f; }

    const float* kb = k + (size_t)bh * N_SEQ * DHEAD;
    const float* vb = v + (size_t)bh * N_SEQ * DHEAD;

    for (int cc = 0; cc < 8; ++cc) {
        int c0 = sp * 512 + cc * 64;
        __syncthreads();
        {   // kp = K^T chunk [kk][j]
            int j = t & 63, kq = t >> 6;
            const float* src = kb + (size_t)(c0 + j) * DHEAD + kq * 16;
            #pragma unroll
            for (int o = 0; o < 16; o += 4) {
                float4 a = *(const float4*)(src + o);
                smem[KP_OFF + (kq * 16 + o + 0) * 68 + j] = a.x;
                smem[KP_OFF + (kq * 16 + o + 1) * 68 + j] = a.y;
                smem[KP_OFF + (kq * 16 + o + 2) * 68 + j] = a.z;
                smem[KP_OFF + (kq * 16 + o + 3) * 68 + j] = a.w;
            }
        }
        {   // wc = V chunk natural [j][d]
            int j = t & 63, dq = t >> 6;
            const float* src = vb + (size_t)(c0 + j) * DHEAD + dq * 16;
            #pragma unroll
            for (int o = 0; o < 16; o += 4)
                *(float4*)&smem[WC_OFF + j * 68 + dq * 16 + o] = *(const float4*)(src + o);
        }
        __syncthreads();

        #pragma unroll
        for (int i = 0; i < 4; ++i)
            #pragma unroll
            for (int j = 0; j < 8; ++j) S[i][j] = 0.f;
        #pragma unroll 4
        for (int kk = 0; kk < DHEAD; ++kk) {
            float4 a4 = *(const float4*)&smem[kk * QT_STRIDE + rb];
            float4 b0 = *(const float4*)&smem[KP_OFF + kk * 68 + lx * 8];
            float4 b1 = *(const float4*)&smem[KP_OFF + kk * 68 + lx * 8 + 4];
            float av[4] = {a4.x, a4.y, a4.z, a4.w};
            #pragma unroll
            for (int i = 0; i < 4; ++i) fma8(S[i], av[i], b0, b1);
        }

        #pragma unroll
        for (int i = 0; i < 4; ++i) {
            float mv = S[i][0];
            #pragma unroll
            for (int j = 1; j < 8; ++j) mv = fmaxf(mv, S[i][j]);
            mv = fmaxf(mv, __shfl_xor(mv, 4, 8));
            mv = fmaxf(mv, __shfl_xor(mv, 2, 8));
            mv = fmaxf(mv, __shfl_xor(mv, 1, 8));
            float nM = fmaxf(M[i], mv);
            float alpha = __expf(M[i] - nM);
            M[i] = nM;
            float rs = 0.f;
            #pragma unroll
            for (int j = 0; j < 8; ++j) { S[i][j] = __expf(S[i][j] - nM); rs += S[i][j]; }
            rs += __shfl_xor(rs, 4, 8);
            rs += __shfl_xor(rs, 2, 8);
            rs += __shfl_xor(rs, 1, 8);
            L[i] = L[i] * alpha + rs;
            #pragma unroll
            for (int j = 0; j < 8; ++j) O[i][j] *= alpha;
        }

        #pragma unroll 2
        for (int lsrc = 0; lsrc < 8; ++lsrc) {
            #pragma unroll
            for (int jq = 0; jq < 8; ++jq) {
                int j = lsrc * 8 + jq;
                float4 v0 = *(const float4*)&smem[WC_OFF + j * 68 + lx * 8];
                float4 v1 = *(const float4*)&smem[WC_OFF + j * 68 + lx * 8 + 4];
                #pragma unroll
                for (int i = 0; i < 4; ++i) {
                    float p = __shfl(S[i][jq], lsrc, 8);
                    fma8(O[i], p, v0, v1);
                }
            }
        }
    }

    int base = (bh * 16 + sp) * MLAND + m0;
    #pragma unroll
    for (int i = 0; i < 4; ++i) {
        int r = rb + i;
        if (lx == 0) { pm[base + r] = M[i]; pl[base + r] = L[i]; }
        float* dst = pO + (size_t)(base + r) * DHEAD + lx * 8;
        *(float4*)dst = make_float4(O[i][0], O[i][1], O[i][2], O[i][3]);
        *(float4*)(dst + 4) = make_float4(O[i][4], O[i][5], O[i][6], O[i][7]);
    }
}

// ---------------------------------------------------------------------------
// 5b) combine 16 splits -> kv
// ---------------------------------------------------------------------------
__global__ __launch_bounds__(64) void k_attn3_combine(
    const float* __restrict__ pO, const float* __restrict__ pm,
    const float* __restrict__ pl, float* __restrict__ kv)
{
    int bh = blockIdx.x >> 8;
    int m  = blockIdx.x & 255;
    int d  = threadIdx.x;
    float M = -1e30f;
    #pragma unroll
    for (int s = 0; s < 16; ++s) M = fmaxf(M, pm[(bh * 16 + s) * MLAND + m]);
    float L = 0.f, O = 0.f;
    #pragma unroll
    for (int s = 0; s < 16; ++s) {
        int base = (bh * 16 + s) * MLAND + m;
        float w = __expf(pm[base] - M);
        L += pl[base] * w;
        O += w * pO[(size_t)base * DHEAD + d];
    }
    kv[((size_t)bh * MLAND + m) * DHEAD + d] = O / L;
}

// ---------------------------------------------------------------------------
// 6) out = softmax(q @ kl^T) @ W + conv33(v). 128 q-rows/block, 4x8/lane.
//    grid (64, NBH), block 256, 2 blk/CU.
// ---------------------------------------------------------------------------
__global__ __launch_bounds__(256, 2) void k_attn1_out(
    const float* __restrict__ q, const float* __restrict__ kl,
    const float* __restrict__ W, const float* __restrict__ v,
    const float* __restrict__ cw, float* __restrict__ out)
{
    __shared__ __align__(16) float smem[FL_SMEM];
    __shared__ float wgt[33];
    int bh = blockIdx.y;
    int r0 = blockIdx.x * 128;
    int t = threadIdx.x;
    int wave = t >> 6, lane = t & 63;
    int ly = lane >> 3, lx = lane & 7;
    int rb = wave * 32 + ly * 4;

    if (t < 33) wgt[t] = cw[(bh & 7) * 33 + t];
    {   // stage 128 q-rows transposed
        int m = t >> 1, k0 = (t & 1) * 32;
        const float* src = q + ((size_t)bh * N_SEQ + r0 + m) * DHEAD + k0;
        #pragma unroll
        for (int kk = 0; kk < 32; kk += 4) {
            float4 a = *(const float4*)(src + kk);
            smem[(k0 + kk + 0) * QT_STRIDE + m] = a.x;
            smem[(k0 + kk + 1) * QT_STRIDE + m] = a.y;
            smem[(k0 + kk + 2) * QT_STRIDE + m] = a.z;
            smem[(k0 + kk + 3) * QT_STRIDE + m] = a.w;
        }
    }

    float S[4][8], O[4][8] = {};
    float M[4], L[4];
    #pragma unroll
    for (int i = 0; i < 4; ++i) { M[i] = -1e30f; L[i] = 0.f; }

    for (int mc = 0; mc < 4; ++mc) {
        __syncthreads();
        {   // kp = kl^T chunk
            int j = t & 63, kq = t >> 6;
            const float* src = kl + ((size_t)bh * MLAND + mc * 64 + j) * DHEAD + kq * 16;
            #pragma unroll
            for (int o = 0; o < 16; o += 4) {
                float4 a = *(const float4*)(src + o);
                smem[KP_OFF + (kq * 16 + o + 0) * 68 + j] = a.x;
                smem[KP_OFF + (kq * 16 + o + 1) * 68 + j] = a.y;
                smem[KP_OFF + (kq * 16 + o + 2) * 68 + j] = a.z;
                smem[KP_OFF + (kq * 16 + o + 3) * 68 + j] = a.w;
            }
        }
        {   // wc = W chunk natural
            int j = t & 63, dq = t >> 6;
            const float* src = W + ((size_t)bh * MLAND + mc * 64 + j) * DHEAD + dq * 16;
            #pragma unroll
            for (int o = 0; o < 16; o += 4)
                *(float4*)&smem[WC_OFF + j * 68 + dq * 16 + o] = *(const float4*)(src + o);
        }
        __syncthreads();

        #pragma unroll
        for (int i = 0; i < 4; ++i)
            #pragma unroll
            for (int j = 0; j < 8; ++j) S[i][j] = 0.f;
        #pragma unroll 4
        for (int kk = 0; kk < DHEAD; ++kk) {
            float4 a4 = *(const float4*)&smem[kk * QT_STRIDE + rb];
            float4 b0 = *(const float4*)&smem[KP_OFF + kk * 68 + lx * 8];
            float4 b1 = *(const float4*)&smem[KP_OFF + kk * 68 + lx * 8 + 4];
            float av[4] = {a4.x, a4.y, a4.z, a4.w};
            #pragma unroll
            for (int i = 0; i < 4; ++i) fma8(S[i], av[i], b0, b1);
        }

        #pragma unroll
        for (int i = 0; i < 4; ++i) {
            float mv = S[i][0];
            #pragma unroll
            for (int j = 1; j < 8; ++j) mv = fmaxf(mv, S[i][j]);
            mv = fmaxf(mv, __shfl_xor(mv, 4, 8));
            mv = fmaxf(mv, __shfl_xor(mv, 2, 8));
            mv = fmaxf(mv, __shfl_xor(mv, 1, 8));
            float nM = fmaxf(M[i], mv);
            float alpha = __expf(M[i] - nM);
            M[i] = nM;
            float rs = 0.f;
            #pragma unroll
            for (int j = 0; j < 8; ++j) { S[i][j] = __expf(S[i][j] - nM); rs += S[i][j]; }
            rs += __shfl_xor(rs, 4, 8);
            rs += __shfl_xor(rs, 2, 8);
            rs += __shfl_xor(rs, 1, 8);
            L[i] = L[i] * alpha + rs;
            #pragma unroll
            for (int j = 0; j < 8; ++j) O[i][j] *= alpha;
        }

        #pragma unroll 2
        for (int lsrc = 0; lsrc < 8; ++lsrc) {
            #pragma unroll
            for (int jq = 0; jq < 8; ++jq) {
                int j = lsrc * 8 + jq;
                float4 v0 = *(const float4*)&smem[WC_OFF + j * 68 + lx * 8];
                float4 v1 = *(const float4*)&smem[WC_OFF + j * 68 + lx * 8 + 4];
                #pragma unroll
                for (int i = 0; i < 4; ++i) {
                    float p = __shfl(S[i][jq], lsrc, 8);
                    fma8(O[i], p, v0, v1);
                }
            }
        }
    }

    float inv[4];
    #pragma unroll
    for (int i = 0; i < 4; ++i) inv[i] = 1.0f / L[i];

    // conv: stage v rows [r0-16, r0+144) at smem base, stride 68
    __syncthreads();
    for (int rr = t; rr < 160; rr += 256) {
        int gr = r0 - 16 + rr;
        bool ok = (gr >= 0) && (gr < N_SEQ);
        const float* src = v + ((size_t)bh * N_SEQ + gr) * DHEAD;
        #pragma unroll
        for (int c = 0; c < 64; c += 4) {
            float4 val = ok ? *(const float4*)(src + c) : make_float4(0.f, 0.f, 0.f, 0.f);
            *(float4*)&smem[rr * 68 + c] = val;
        }
    }
    __syncthreads();

    float res[4][8] = {};
    #pragma unroll
    for (int w = 0; w < 36; ++w) {
        float4 va = *(const float4*)&smem[(rb + w) * 68 + lx * 8];
        float4 vb4 = *(const float4*)&smem[(rb + w) * 68 + lx * 8 + 4];
        #pragma unroll
        for (int i = 0; i < 4; ++i) {
            if (w - i >= 0 && w - i <= 32) {
                float wv = wgt[w - i];
                fma8(res[i], wv, va, vb4);
            }
        }
    }

    #pragma unroll
    for (int i = 0; i < 4; ++i) {
        float* dst = out + ((size_t)bh * N_SEQ + r0 + rb + i) * DHEAD + lx * 8;
        *(float4*)dst = make_float4(O[i][0] * inv[i] + res[i][0], O[i][1] * inv[i] + res[i][1],
                                    O[i][2] * inv[i] + res[i][2], O[i][3] * inv[i] + res[i][3]);
        *(float4*)(dst + 4) = make_float4(O[i][4] * inv[i] + res[i][4], O[i][5] * inv[i] + res[i][5],
                                          O[i][6] * inv[i] + res[i][6], O[i][7] * inv[i] + res[i][7]);
    }
}

// ---------------------------------------------------------------------------
// launch
// ---------------------------------------------------------------------------
extern "C" void kernel_launch(void* const* d_in, const int* in_sizes, int n_in,
                              void* d_out, int out_size, void* d_ws, size_t ws_size,
                              hipStream_t stream)
{
    (void)in_sizes; (void)n_in; (void)out_size; (void)ws_size;
    const float* q  = (const float*)d_in[0];
    const float* k  = (const float*)d_in[1];
    const float* v  = (const float*)d_in[2];
    const float* cw = (const float*)d_in[3];
    float* out = (float*)d_out;
    float* ws  = (float*)d_ws;

    const size_t LM = (size_t)NBH * MLAND * DHEAD;   // 262144 floats
    const size_t MM = (size_t)NBH * MLAND * MLAND;   // 1048576 floats
    float* ql  = ws;
    float* kl  = ql  + LM;
    float* x   = kl  + LM;   // attn2
    float* z   = x   + MM;
    float* z2  = z   + MM;
    float* xz  = z2  + MM;
    float* t2  = xz  + MM;
    float* t3  = t2  + MM;
    float* kv  = t3  + MM;
    float* W   = kv  + LM;
    float* scl = W   + LM;   // [0,1]=scales
    float* pm  = scl + 16;
    float* pl  = pm + (size_t)NBH * 16 * MLAND;

    // attn3 partials: pO spans z2..t3 (4*MM floats), dead before pinv.
    float* pO = z2;

    hipMemsetAsync(scl, 0, 32, stream);

    k_landmarks<<<dim3(NBH * MLAND, 2), 64, 0, stream>>>(q, k, ql, kl);
    k_sim2_softmax<<<NBH * MLAND, 256, 0, stream>>>(ql, kl, x);
    k_scale_reduce<<<NBH, 256, 0, stream>>>(x, scl);
    k_zinit<<<dim3(8, 8, NBH), 256, 0, stream>>>(x, z, scl);

    k_attn3_partial<<<dim3(16, 2, NBH), 256, 0, stream>>>(ql, k, v, pO, pm, pl);
    k_attn3_combine<<<NBH * MLAND, 64, 0, stream>>>(pO, pm, pl, kv);

    // Moore-Penrose: z' = 0.25*z@(13I - xz@(15I - xz@(7I - xz))), xz = x@z
    float* zc = z;
    float* zn = z2;
    for (int it = 0; it < 6; ++it) {
        k_bmm512<<<dim3(4, 4, NBH), 512, 0, stream>>>(x,  zc, xz, 256,  0.f,  1.f, 1.f);
        k_bmm512<<<dim3(4, 4, NBH), 512, 0, stream>>>(xz, xz, t2, 256,  7.f, -1.f, 1.f);
        k_bmm512<<<dim3(4, 4, NBH), 512, 0, stream>>>(xz, t2, t3, 256, 15.f, -1.f, 1.f);
        k_bmm512<<<dim3(4, 4, NBH), 512, 0, stream>>>(zc, t3, zn, 256, 13.f, -1.f, 0.25f);
        float* tt = zc; zc = zn; zn = tt;
    }
    // W = attn2_inv @ kv   [256x256 @ 256x64]
    k_bmm512<<<dim3(1, 4, NBH), 512, 0, stream>>>(zc, kv, W, 64, 0.f, 1.f, 1.f);

    k_attn1_out<<<dim3(64, NBH), 256, 0, stream>>>(q, kl, W, v, cw, out);
}

// Round 7
// 790.532 us; speedup vs baseline: 1.8633x; 1.1931x over previous
//
#include <hip/hip_runtime.h>

// ---------------------------------------------------------------------------
// Nystrom attention, fp32. b=2,h=8,n=8192,d=64, m=256 landmarks, conv33.
// Round 7: pinv chain on MFMA (bf16 hi+lo split, 3 products, fp32 acc).
// ---------------------------------------------------------------------------

#define N_SEQ 8192
#define NBH   16
#define MLAND 256
#define DHEAD 64

// flash kernels' shared layout (floats): Qt [64][132] | KP [64][68] | WC [64][68]
#define QT_STRIDE 132
#define KP_OFF    8448           // 64*132
#define WC_OFF    12800          // + 64*68
#define FL_SMEM   17152          // + 64*68  (68.6 KB)

typedef __attribute__((ext_vector_type(8))) short bfrag;
typedef __attribute__((ext_vector_type(4))) float f32x4;

__device__ __forceinline__ void fma8(float (&o)[8], float p, const float4& a, const float4& b) {
    o[0] += p * a.x; o[1] += p * a.y; o[2] += p * a.z; o[3] += p * a.w;
    o[4] += p * b.x; o[5] += p * b.y; o[6] += p * b.z; o[7] += p * b.w;
}

__device__ __forceinline__ unsigned short f2bf(float f) {
    unsigned u = __float_as_uint(f);
    unsigned r = u + 0x7fffu + ((u >> 16) & 1u);
    return (unsigned short)(r >> 16);
}
__device__ __forceinline__ float bf2f(unsigned short h) {
    return __uint_as_float(((unsigned)h) << 16);
}

// ---------------------------------------------------------------------------
// 1) landmark means
// ---------------------------------------------------------------------------
__global__ __launch_bounds__(64) void k_landmarks(
    const float* __restrict__ q, const float* __restrict__ k,
    float* __restrict__ ql, float* __restrict__ kl)
{
    int mi = blockIdx.x & 255;
    int bh = blockIdx.x >> 8;
    const float* src = blockIdx.y ? k : q;
    float*       dst = blockIdx.y ? kl : ql;
    int t = threadIdx.x;
    const float* s = src + ((size_t)bh * N_SEQ + (size_t)mi * 32) * DHEAD;
    float acc = 0.f;
    #pragma unroll
    for (int j = 0; j < 32; ++j) acc += s[j * DHEAD + t];
    dst[((size_t)bh * MLAND + mi) * DHEAD + t] = acc * (1.f / 32.f);
}

// ---------------------------------------------------------------------------
// 2) attn2 = softmax(ql @ kl^T) rowwise
// ---------------------------------------------------------------------------
__global__ __launch_bounds__(256) void k_sim2_softmax(
    const float* __restrict__ ql, const float* __restrict__ kl,
    float* __restrict__ attn2)
{
    int bh = blockIdx.x >> 8;
    int i  = blockIdx.x & 255;
    int t  = threadIdx.x;
    __shared__ float qrow[DHEAD];
    __shared__ float wred[8];
    if (t < DHEAD) qrow[t] = ql[((size_t)bh * MLAND + i) * DHEAD + t];
    __syncthreads();
    const float* krow = kl + ((size_t)bh * MLAND + t) * DHEAD;
    float s = 0.f;
    #pragma unroll
    for (int kk = 0; kk < DHEAD; kk += 4) {
        float4 k4 = *(const float4*)(krow + kk);
        s += qrow[kk] * k4.x + qrow[kk + 1] * k4.y + qrow[kk + 2] * k4.z + qrow[kk + 3] * k4.w;
    }
    float m = s;
    #pragma unroll
    for (int o = 32; o > 0; o >>= 1) m = fmaxf(m, __shfl_xor(m, o, 64));
    int wave = t >> 6, lane = t & 63;
    if (lane == 0) wred[wave] = m;
    __syncthreads();
    float bm = fmaxf(fmaxf(wred[0], wred[1]), fmaxf(wred[2], wred[3]));
    float e = __expf(s - bm);
    float sum = e;
    #pragma unroll
    for (int o = 32; o > 0; o >>= 1) sum += __shfl_xor(sum, o, 64);
    if (lane == 0) wred[4 + wave] = sum;
    __syncthreads();
    float bs = wred[4] + wred[5] + wred[6] + wred[7];
    attn2[((size_t)bh * MLAND + i) * MLAND + t] = e / bs;
}

// ---------------------------------------------------------------------------
// 3a) global max of row-sums and col-sums of attn2
// ---------------------------------------------------------------------------
__global__ __launch_bounds__(256) void k_scale_reduce(
    const float* __restrict__ x, float* __restrict__ scl)
{
    int bh = blockIdx.x, t = threadIdx.x;
    const float* xb = x + (size_t)bh * MLAND * MLAND;
    float colsum = 0.f, rowsum = 0.f;
    for (int i = 0; i < MLAND; ++i) colsum += xb[(size_t)i * MLAND + t];
    for (int j = 0; j < MLAND; ++j) rowsum += xb[(size_t)t * MLAND + j];
    __shared__ float red[256];
    red[t] = rowsum;
    __syncthreads();
    for (int o = 128; o > 0; o >>= 1) {
        if (t < o) red[t] = fmaxf(red[t], red[t + o]);
        __syncthreads();
    }
    if (t == 0) atomicMax((unsigned int*)&scl[0], __float_as_uint(red[0]));
    __syncthreads();
    red[t] = colsum;
    __syncthreads();
    for (int o = 128; o > 0; o >>= 1) {
        if (t < o) red[t] = fmaxf(red[t], red[t + o]);
        __syncthreads();
    }
    if (t == 0) atomicMax((unsigned int*)&scl[1], __float_as_uint(red[0]));
}

// ---------------------------------------------------------------------------
// 3b) z0 = attn2^T / (scl[0]*scl[1])
// ---------------------------------------------------------------------------
__global__ __launch_bounds__(256) void k_zinit(
    const float* __restrict__ x, float* __restrict__ z,
    const float* __restrict__ scl)
{
    __shared__ float tile[32][33];
    int bh = blockIdx.z;
    int i0 = blockIdx.y * 32, j0 = blockIdx.x * 32;
    int t = threadIdx.x;
    int lx = t & 31, ly = t >> 5;
    const float* xb = x + (size_t)bh * MLAND * MLAND;
    float*       zb = z + (size_t)bh * MLAND * MLAND;
    #pragma unroll
    for (int p = 0; p < 4; ++p)
        tile[ly + 8 * p][lx] = xb[(size_t)(i0 + ly + 8 * p) * MLAND + j0 + lx];
    __syncthreads();
    float inv = 1.0f / (scl[0] * scl[1]);
    #pragma unroll
    for (int p = 0; p < 4; ++p)
        zb[(size_t)(j0 + ly + 8 * p) * MLAND + i0 + lx] = tile[lx][ly + 8 * p] * inv;
}

// ---------------------------------------------------------------------------
// 4) MFMA batched C = outscale * (A @ (diag*I + bscale*B)); M=K=256, N param.
//    bf16 hi+lo split: C = Ah*Bh + Ah*Bl + Al*Bh (fp32 acc, ~2^-16 rel err).
//    64x64 tile, 256 threads (4 waves), wave = 16x64 strip (4 f32x4 accs).
//    LDS: Ah/Al [m][k] natural (72-ushort rows), Bh/Bl [n][k] transposed.
// ---------------------------------------------------------------------------
__global__ __launch_bounds__(256) void k_bmm_mfma(
    const float* __restrict__ A, const float* __restrict__ B, float* __restrict__ C,
    int N, float diag, float bscale, float outscale)
{
    __shared__ unsigned short sm[4 * 64 * 72];   // Ah | Al | Bh | Bl  (36.9 KB)
    unsigned short* Ah = sm;
    unsigned short* Al = sm + 64 * 72;
    unsigned short* Bh = sm + 2 * 64 * 72;
    unsigned short* Bl = sm + 3 * 64 * 72;

    int bh = blockIdx.z;
    const float* Ab = A + (size_t)bh * 65536;
    const float* Bb = B + (size_t)bh * 256 * N;
    float*       Cb = C + (size_t)bh * 256 * N;
    int m0 = blockIdx.y * 64, n0 = blockIdx.x * 64;
    int t = threadIdx.x;
    int wave = t >> 6, lane = t & 63;
    int l15 = lane & 15, quad = lane >> 4;

    f32x4 acc[4] = {};

    for (int kc = 0; kc < 256; kc += 64) {
        __syncthreads();
        {   // stage A rows natural [m][k]: thread: row m=t&63, 16 k's
            int m = t & 63, ks = (t >> 6) * 16;
            const float* src = Ab + (size_t)(m0 + m) * 256 + kc + ks;
            unsigned short h[16], l[16];
            #pragma unroll
            for (int o = 0; o < 16; o += 4) {
                float4 a = *(const float4*)(src + o);
                float vv[4] = {a.x, a.y, a.z, a.w};
                #pragma unroll
                for (int u = 0; u < 4; ++u) {
                    h[o + u] = f2bf(vv[u]);
                    l[o + u] = f2bf(vv[u] - bf2f(h[o + u]));
                }
            }
            // pack and write 16 ushorts = 2x16B each
            unsigned* dh = (unsigned*)&Ah[m * 72 + ks];
            unsigned* dl = (unsigned*)&Al[m * 72 + ks];
            #pragma unroll
            for (int o = 0; o < 8; ++o) {
                dh[o] = (unsigned)h[2 * o] | ((unsigned)h[2 * o + 1] << 16);
                dl[o] = (unsigned)l[2 * o] | ((unsigned)l[2 * o + 1] << 16);
            }
        }
        {   // stage B transposed [n][k] with fused affine: thread: k=t&63, 16 n's
            int kk = t & 63, ns = (t >> 6) * 16;
            int gk = kc + kk;
            const float* src = Bb + (size_t)gk * N + n0 + ns;
            #pragma unroll
            for (int o = 0; o < 16; o += 4) {
                float4 bv = *(const float4*)(src + o);
                float vv[4] = {bv.x, bv.y, bv.z, bv.w};
                #pragma unroll
                for (int u = 0; u < 4; ++u) {
                    float val = bscale * vv[u];
                    if (gk == n0 + ns + o + u) val += diag;
                    unsigned short hh = f2bf(val);
                    Bh[(ns + o + u) * 72 + kk] = hh;
                    Bl[(ns + o + u) * 72 + kk] = f2bf(val - bf2f(hh));
                }
            }
        }
        __syncthreads();

        #pragma unroll
        for (int k0 = 0; k0 < 64; k0 += 32) {
            int kf = k0 + quad * 8;
            int am = wave * 16 + l15;
            bfrag ah = *(const bfrag*)&Ah[am * 72 + kf];
            bfrag al = *(const bfrag*)&Al[am * 72 + kf];
            #pragma unroll
            for (int j = 0; j < 4; ++j) {
                int bn = j * 16 + l15;
                bfrag bhf = *(const bfrag*)&Bh[bn * 72 + kf];
                bfrag blf = *(const bfrag*)&Bl[bn * 72 + kf];
                acc[j] = __builtin_amdgcn_mfma_f32_16x16x32_bf16(al, bhf, acc[j], 0, 0, 0);
                acc[j] = __builtin_amdgcn_mfma_f32_16x16x32_bf16(ah, blf, acc[j], 0, 0, 0);
                acc[j] = __builtin_amdgcn_mfma_f32_16x16x32_bf16(ah, bhf, acc[j], 0, 0, 0);
            }
        }
    }

    // D layout: row = quad*4 + r (within 16-row wave strip), col = lane&15
    #pragma unroll
    for (int j = 0; j < 4; ++j) {
        #pragma unroll
        for (int r = 0; r < 4; ++r) {
            int row = m0 + wave * 16 + quad * 4 + r;
            Cb[(size_t)row * N + n0 + j * 16 + l15] = acc[j][r] * outscale;
        }
    }
}

// ---------------------------------------------------------------------------
// 5a) attn3 flash partial: 128 landmarks/block, 512-key split.
// ---------------------------------------------------------------------------
__global__ __launch_bounds__(256, 2) void k_attn3_partial(
    const float* __restrict__ ql, const float* __restrict__ k,
    const float* __restrict__ v, float* __restrict__ pO,
    float* __restrict__ pm, float* __restrict__ pl)
{
    __shared__ __align__(16) float smem[FL_SMEM];
    int sp = blockIdx.x;
    int m0 = blockIdx.y * 128;
    int bh = blockIdx.z;
    int t = threadIdx.x;
    int wave = t >> 6, lane = t & 63;
    int ly = lane >> 3, lx = lane & 7;
    int rb = wave * 32 + ly * 4;

    {   // stage 128 q-rows transposed
        int m = t >> 1, k0 = (t & 1) * 32;
        const float* src = ql + ((size_t)bh * MLAND + m0 + m) * DHEAD + k0;
        #pragma unroll
        for (int kk = 0; kk < 32; kk += 4) {
            float4 a = *(const float4*)(src + kk);
            smem[(k0 + kk + 0) * QT_STRIDE + m] = a.x;
            smem[(k0 + kk + 1) * QT_STRIDE + m] = a.y;
            smem[(k0 + kk + 2) * QT_STRIDE + m] = a.z;
            smem[(k0 + kk + 3) * QT_STRIDE + m] = a.w;
        }
    }

    float S[4][8], O[4][8] = {};
    float M[4], L[4];
    #pragma unroll
    for (int i = 0; i < 4; ++i) { M[i] = -1e30f; L[i] = 0.f; }

    const float* kb = k + (size_t)bh * N_SEQ * DHEAD;
    const float* vb = v + (size_t)bh * N_SEQ * DHEAD;

    for (int cc = 0; cc < 8; ++cc) {
        int c0 = sp * 512 + cc * 64;
        __syncthreads();
        {   // kp = K^T chunk [kk][j]
            int j = t & 63, kq = t >> 6;
            const float* src = kb + (size_t)(c0 + j) * DHEAD + kq * 16;
            #pragma unroll
            for (int o = 0; o < 16; o += 4) {
                float4 a = *(const float4*)(src + o);
                smem[KP_OFF + (kq * 16 + o + 0) * 68 + j] = a.x;
                smem[KP_OFF + (kq * 16 + o + 1) * 68 + j] = a.y;
                smem[KP_OFF + (kq * 16 + o + 2) * 68 + j] = a.z;
                smem[KP_OFF + (kq * 16 + o + 3) * 68 + j] = a.w;
            }
        }
        {   // wc = V chunk natural [j][d]
            int j = t & 63, dq = t >> 6;
            const float* src = vb + (size_t)(c0 + j) * DHEAD + dq * 16;
            #pragma unroll
            for (int o = 0; o < 16; o += 4)
                *(float4*)&smem[WC_OFF + j * 68 + dq * 16 + o] = *(const float4*)(src + o);
        }
        __syncthreads();

        #pragma unroll
        for (int i = 0; i < 4; ++i)
            #pragma unroll
            for (int j = 0; j < 8; ++j) S[i][j] = 0.f;
        #pragma unroll 4
        for (int kk = 0; kk < DHEAD; ++kk) {
            float4 a4 = *(const float4*)&smem[kk * QT_STRIDE + rb];
            float4 b0 = *(const float4*)&smem[KP_OFF + kk * 68 + lx * 8];
            float4 b1 = *(const float4*)&smem[KP_OFF + kk * 68 + lx * 8 + 4];
            float av[4] = {a4.x, a4.y, a4.z, a4.w};
            #pragma unroll
            for (int i = 0; i < 4; ++i) fma8(S[i], av[i], b0, b1);
        }

        #pragma unroll
        for (int i = 0; i < 4; ++i) {
            float mv = S[i][0];
            #pragma unroll
            for (int j = 1; j < 8; ++j) mv = fmaxf(mv, S[i][j]);
            mv = fmaxf(mv, __shfl_xor(mv, 4, 8));
            mv = fmaxf(mv, __shfl_xor(mv, 2, 8));
            mv = fmaxf(mv, __shfl_xor(mv, 1, 8));
            float nM = fmaxf(M[i], mv);
            float alpha = __expf(M[i] - nM);
            M[i] = nM;
            float rs = 0.f;
            #pragma unroll
            for (int j = 0; j < 8; ++j) { S[i][j] = __expf(S[i][j] - nM); rs += S[i][j]; }
            rs += __shfl_xor(rs, 4, 8);
            rs += __shfl_xor(rs, 2, 8);
            rs += __shfl_xor(rs, 1, 8);
            L[i] = L[i] * alpha + rs;
            #pragma unroll
            for (int j = 0; j < 8; ++j) O[i][j] *= alpha;
        }

        #pragma unroll 2
        for (int lsrc = 0; lsrc < 8; ++lsrc) {
            #pragma unroll
            for (int jq = 0; jq < 8; ++jq) {
                int j = lsrc * 8 + jq;
                float4 v0 = *(const float4*)&smem[WC_OFF + j * 68 + lx * 8];
                float4 v1 = *(const float4*)&smem[WC_OFF + j * 68 + lx * 8 + 4];
                #pragma unroll
                for (int i = 0; i < 4; ++i) {
                    float p = __shfl(S[i][jq], lsrc, 8);
                    fma8(O[i], p, v0, v1);
                }
            }
        }
    }

    int base = (bh * 16 + sp) * MLAND + m0;
    #pragma unroll
    for (int i = 0; i < 4; ++i) {
        int r = rb + i;
        if (lx == 0) { pm[base + r] = M[i]; pl[base + r] = L[i]; }
        float* dst = pO + (size_t)(base + r) * DHEAD + lx * 8;
        *(float4*)dst = make_float4(O[i][0], O[i][1], O[i][2], O[i][3]);
        *(float4*)(dst + 4) = make_float4(O[i][4], O[i][5], O[i][6], O[i][7]);
    }
}

// ---------------------------------------------------------------------------
// 5b) combine 16 splits -> kv
// ---------------------------------------------------------------------------
__global__ __launch_bounds__(64) void k_attn3_combine(
    const float* __restrict__ pO, const float* __restrict__ pm,
    const float* __restrict__ pl, float* __restrict__ kv)
{
    int bh = blockIdx.x >> 8;
    int m  = blockIdx.x & 255;
    int d  = threadIdx.x;
    float M = -1e30f;
    #pragma unroll
    for (int s = 0; s < 16; ++s) M = fmaxf(M, pm[(bh * 16 + s) * MLAND + m]);
    float L = 0.f, O = 0.f;
    #pragma unroll
    for (int s = 0; s < 16; ++s) {
        int base = (bh * 16 + s) * MLAND + m;
        float w = __expf(pm[base] - M);
        L += pl[base] * w;
        O += w * pO[(size_t)base * DHEAD + d];
    }
    kv[((size_t)bh * MLAND + m) * DHEAD + d] = O / L;
}

// ---------------------------------------------------------------------------
// 6) out = softmax(q @ kl^T) @ W + conv33(v). 128 q-rows/block, 4x8/lane.
// ---------------------------------------------------------------------------
__global__ __launch_bounds__(256, 2) void k_attn1_out(
    const float* __restrict__ q, const float* __restrict__ kl,
    const float* __restrict__ W, const float* __restrict__ v,
    const float* __restrict__ cw, float* __restrict__ out)
{
    __shared__ __align__(16) float smem[FL_SMEM];
    __shared__ float wgt[33];
    int bh = blockIdx.y;
    int r0 = blockIdx.x * 128;
    int t = threadIdx.x;
    int wave = t >> 6, lane = t & 63;
    int ly = lane >> 3, lx = lane & 7;
    int rb = wave * 32 + ly * 4;

    if (t < 33) wgt[t] = cw[(bh & 7) * 33 + t];
    {   // stage 128 q-rows transposed
        int m = t >> 1, k0 = (t & 1) * 32;
        const float* src = q + ((size_t)bh * N_SEQ + r0 + m) * DHEAD + k0;
        #pragma unroll
        for (int kk = 0; kk < 32; kk += 4) {
            float4 a = *(const float4*)(src + kk);
            smem[(k0 + kk + 0) * QT_STRIDE + m] = a.x;
            smem[(k0 + kk + 1) * QT_STRIDE + m] = a.y;
            smem[(k0 + kk + 2) * QT_STRIDE + m] = a.z;
            smem[(k0 + kk + 3) * QT_STRIDE + m] = a.w;
        }
    }

    float S[4][8], O[4][8] = {};
    float M[4], L[4];
    #pragma unroll
    for (int i = 0; i < 4; ++i) { M[i] = -1e30f; L[i] = 0.f; }

    for (int mc = 0; mc < 4; ++mc) {
        __syncthreads();
        {   // kp = kl^T chunk
            int j = t & 63, kq = t >> 6;
            const float* src = kl + ((size_t)bh * MLAND + mc * 64 + j) * DHEAD + kq * 16;
            #pragma unroll
            for (int o = 0; o < 16; o += 4) {
                float4 a = *(const float4*)(src + o);
                smem[KP_OFF + (kq * 16 + o + 0) * 68 + j] = a.x;
                smem[KP_OFF + (kq * 16 + o + 1) * 68 + j] = a.y;
                smem[KP_OFF + (kq * 16 + o + 2) * 68 + j] = a.z;
                smem[KP_OFF + (kq * 16 + o + 3) * 68 + j] = a.w;
            }
        }
        {   // wc = W chunk natural
            int j = t & 63, dq = t >> 6;
            const float* src = W + ((size_t)bh * MLAND + mc * 64 + j) * DHEAD + dq * 16;
            #pragma unroll
            for (int o = 0; o < 16; o += 4)
                *(float4*)&smem[WC_OFF + j * 68 + dq * 16 + o] = *(const float4*)(src + o);
        }
        __syncthreads();

        #pragma unroll
        for (int i = 0; i < 4; ++i)
            #pragma unroll
            for (int j = 0; j < 8; ++j) S[i][j] = 0.f;
        #pragma unroll 4
        for (int kk = 0; kk < DHEAD; ++kk) {
            float4 a4 = *(const float4*)&smem[kk * QT_STRIDE + rb];
            float4 b0 = *(const float4*)&smem[KP_OFF + kk * 68 + lx * 8];
            float4 b1 = *(const float4*)&smem[KP_OFF + kk * 68 + lx * 8 + 4];
            float av[4] = {a4.x, a4.y, a4.z, a4.w};
            #pragma unroll
            for (int i = 0; i < 4; ++i) fma8(S[i], av[i], b0, b1);
        }

        #pragma unroll
        for (int i = 0; i < 4; ++i) {
            float mv = S[i][0];
            #pragma unroll
            for (int j = 1; j < 8; ++j) mv = fmaxf(mv, S[i][j]);
            mv = fmaxf(mv, __shfl_xor(mv, 4, 8));
            mv = fmaxf(mv, __shfl_xor(mv, 2, 8));
            mv = fmaxf(mv, __shfl_xor(mv, 1, 8));
            float nM = fmaxf(M[i], mv);
            float alpha = __expf(M[i] - nM);
            M[i] = nM;
            float rs = 0.f;
            #pragma unroll
            for (int j = 0; j < 8; ++j) { S[i][j] = __expf(S[i][j] - nM); rs += S[i][j]; }
            rs += __shfl_xor(rs, 4, 8);
            rs += __shfl_xor(rs, 2, 8);
            rs += __shfl_xor(rs, 1, 8);
            L[i] = L[i] * alpha + rs;
            #pragma unroll
            for (int j = 0; j < 8; ++j) O[i][j] *= alpha;
        }

        #pragma unroll 2
        for (int lsrc = 0; lsrc < 8; ++lsrc) {
            #pragma unroll
            for (int jq = 0; jq < 8; ++jq) {
                int j = lsrc * 8 + jq;
                float4 v0 = *(const float4*)&smem[WC_OFF + j * 68 + lx * 8];
                float4 v1 = *(const float4*)&smem[WC_OFF + j * 68 + lx * 8 + 4];
                #pragma unroll
                for (int i = 0; i < 4; ++i) {
                    float p = __shfl(S[i][jq], lsrc, 8);
                    fma8(O[i], p, v0, v1);
                }
            }
        }
    }

    float inv[4];
    #pragma unroll
    for (int i = 0; i < 4; ++i) inv[i] = 1.0f / L[i];

    // conv: stage v rows [r0-16, r0+144) at smem base, stride 68
    __syncthreads();
    for (int rr = t; rr < 160; rr += 256) {
        int gr = r0 - 16 + rr;
        bool ok = (gr >= 0) && (gr < N_SEQ);
        const float* src = v + ((size_t)bh * N_SEQ + gr) * DHEAD;
        #pragma unroll
        for (int c = 0; c < 64; c += 4) {
            float4 val = ok ? *(const float4*)(src + c) : make_float4(0.f, 0.f, 0.f, 0.f);
            *(float4*)&smem[rr * 68 + c] = val;
        }
    }
    __syncthreads();

    float res[4][8] = {};
    #pragma unroll
    for (int w = 0; w < 36; ++w) {
        float4 va = *(const float4*)&smem[(rb + w) * 68 + lx * 8];
        float4 vb4 = *(const float4*)&smem[(rb + w) * 68 + lx * 8 + 4];
        #pragma unroll
        for (int i = 0; i < 4; ++i) {
            if (w - i >= 0 && w - i <= 32) {
                float wv = wgt[w - i];
                fma8(res[i], wv, va, vb4);
            }
        }
    }

    #pragma unroll
    for (int i = 0; i < 4; ++i) {
        float* dst = out + ((size_t)bh * N_SEQ + r0 + rb + i) * DHEAD + lx * 8;
        *(float4*)dst = make_float4(O[i][0] * inv[i] + res[i][0], O[i][1] * inv[i] + res[i][1],
                                    O[i][2] * inv[i] + res[i][2], O[i][3] * inv[i] + res[i][3]);
        *(float4*)(dst + 4) = make_float4(O[i][4] * inv[i] + res[i][4], O[i][5] * inv[i] + res[i][5],
                                          O[i][6] * inv[i] + res[i][6], O[i][7] * inv[i] + res[i][7]);
    }
}

// ---------------------------------------------------------------------------
// launch
// ---------------------------------------------------------------------------
extern "C" void kernel_launch(void* const* d_in, const int* in_sizes, int n_in,
                              void* d_out, int out_size, void* d_ws, size_t ws_size,
                              hipStream_t stream)
{
    (void)in_sizes; (void)n_in; (void)out_size; (void)ws_size;
    const float* q  = (const float*)d_in[0];
    const float* k  = (const float*)d_in[1];
    const float* v  = (const float*)d_in[2];
    const float* cw = (const float*)d_in[3];
    float* out = (float*)d_out;
    float* ws  = (float*)d_ws;

    const size_t LM = (size_t)NBH * MLAND * DHEAD;   // 262144 floats
    const size_t MM = (size_t)NBH * MLAND * MLAND;   // 1048576 floats
    float* ql  = ws;
    float* kl  = ql  + LM;
    float* x   = kl  + LM;   // attn2
    float* z   = x   + MM;
    float* z2  = z   + MM;
    float* xz  = z2  + MM;
    float* t2  = xz  + MM;
    float* t3  = t2  + MM;
    float* kv  = t3  + MM;
    float* W   = kv  + LM;
    float* scl = W   + LM;   // [0,1]=scales
    float* pm  = scl + 16;
    float* pl  = pm + (size_t)NBH * 16 * MLAND;

    // attn3 partials: pO spans z2..t3 (4*MM floats), dead before pinv.
    float* pO = z2;

    hipMemsetAsync(scl, 0, 32, stream);

    k_landmarks<<<dim3(NBH * MLAND, 2), 64, 0, stream>>>(q, k, ql, kl);
    k_sim2_softmax<<<NBH * MLAND, 256, 0, stream>>>(ql, kl, x);
    k_scale_reduce<<<NBH, 256, 0, stream>>>(x, scl);
    k_zinit<<<dim3(8, 8, NBH), 256, 0, stream>>>(x, z, scl);

    k_attn3_partial<<<dim3(16, 2, NBH), 256, 0, stream>>>(ql, k, v, pO, pm, pl);
    k_attn3_combine<<<NBH * MLAND, 64, 0, stream>>>(pO, pm, pl, kv);

    // Moore-Penrose: z' = 0.25*z@(13I - xz@(15I - xz@(7I - xz))), xz = x@z
    float* zc = z;
    float* zn = z2;
    for (int it = 0; it < 6; ++it) {
        k_bmm_mfma<<<dim3(4, 4, NBH), 256, 0, stream>>>(x,  zc, xz, 256,  0.f,  1.f, 1.f);
        k_bmm_mfma<<<dim3(4, 4, NBH), 256, 0, stream>>>(xz, xz, t2, 256,  7.f, -1.f, 1.f);
        k_bmm_mfma<<<dim3(4, 4, NBH), 256, 0, stream>>>(xz, t2, t3, 256, 15.f, -1.f, 1.f);
        k_bmm_mfma<<<dim3(4, 4, NBH), 256, 0, stream>>>(zc, t3, zn, 256, 13.f, -1.f, 0.25f);
        float* tt = zc; zc = zn; zn = tt;
    }
    // W = attn2_inv @ kv   [256x256 @ 256x64]
    k_bmm_mfma<<<dim3(1, 4, NBH), 256, 0, stream>>>(zc, kv, W, 64, 0.f, 1.f, 1.f);

    k_attn1_out<<<dim3(64, NBH), 256, 0, stream>>>(q, kl, W, v, cw, out);
}